// Round 1
// baseline (1079.207 us; speedup 1.0000x reference)
//
#include <hip/hip_runtime.h>

// out = relu(x @ W1) @ W2
// x: [N,155] fp32, W1: [155,128] fp32, W2: [128,3] fp32, out: [N,3] fp32.
// v3: drop the x LDS tile entirely. MFMA A-frags are loaded per-lane directly
//     from global (each lane's k-slice = 8 consecutive floats of one row) and
//     converted fp32->bf16 in-register. LDS holds only W1^T (43 KB) ->
//     3 blocks/CU (was 1), no per-tile __syncthreads, waves fully decoupled.

#define N_TOTAL 1048576
#define IN_DIM 155
#define HIDDEN 128
#define ROWS_PER_BLOCK 1024
#define TILE_ROWS 128
#define NTILES 8   // ROWS_PER_BLOCK / TILE_ROWS
#define XK 168     // LDS k-stride (bf16): 336B rows, 16B aligned, <=2-way banks

typedef __attribute__((ext_vector_type(8))) short short8;   // 8 bf16 MFMA A/B frag
typedef __attribute__((ext_vector_type(4))) float floatx4;  // MFMA C/D frag

static __device__ __forceinline__ unsigned short f2bf(float f) {
  // round-to-nearest-even fp32 -> bf16 (inputs are finite normals)
  unsigned int u = __builtin_bit_cast(unsigned int, f);
  u += 0x7fffu + ((u >> 16) & 1u);
  return (unsigned short)(u >> 16);
}

static __device__ __forceinline__ void epilogue_16rows(
    const floatx4* acc, const float w2r[8][3], int ln, int quad,
    float* __restrict__ out, size_t row0) {
  // acc[t][r] = h[row0 + quad*4 + r][16*t + ln]
  float part[4][3];
#pragma unroll
  for (int r = 0; r < 4; ++r)
#pragma unroll
    for (int c = 0; c < 3; ++c) part[r][c] = 0.f;

#pragma unroll
  for (int t = 0; t < 8; ++t) {
#pragma unroll
    for (int r = 0; r < 4; ++r) {
      const float hv = fmaxf(acc[t][r], 0.f);
      part[r][0] = fmaf(hv, w2r[t][0], part[r][0]);
      part[r][1] = fmaf(hv, w2r[t][1], part[r][1]);
      part[r][2] = fmaf(hv, w2r[t][2], part[r][2]);
    }
  }
  // reduce k-partials across the 16 lanes of each quad
#pragma unroll
  for (int off = 1; off < 16; off <<= 1) {
#pragma unroll
    for (int r = 0; r < 4; ++r)
#pragma unroll
      for (int c = 0; c < 3; ++c) part[r][c] += __shfl_xor(part[r][c], off, 16);
  }
  // lanes 0..11 of each quad write the 12 outputs
#pragma unroll
  for (int r = 0; r < 4; ++r)
#pragma unroll
    for (int c = 0; c < 3; ++c)
      if (ln == r * 3 + c) out[(row0 + quad * 4 + r) * 3 + c] = part[r][c];
}

__global__ __launch_bounds__(256, 3) void fused_mlp_kernel(
    const float* __restrict__ x, const float* __restrict__ W1,
    const float* __restrict__ W2, float* __restrict__ out) {
  __shared__ __align__(16) unsigned short w1s[HIDDEN * XK];  // W1^T bf16, k-padded

  const int tid = threadIdx.x;
  const int ln = tid & 15;
  const int quad = (tid >> 4) & 3;
  const int wave = tid >> 6;

  // ---- stage W1^T as bf16 into LDS (once per block, coalesced global reads) ----
  for (int idx = tid; idx < IN_DIM * HIDDEN; idx += 256) {
    const int k = idx >> 7;
    const int n = idx & 127;
    w1s[n * XK + k] = f2bf(W1[idx]);
  }
  for (int idx = tid; idx < HIDDEN * 8; idx += 256) {  // zero k-pad 155..159
    const int n = idx >> 3;
    const int k = 152 + (idx & 7);
    if (k >= IN_DIM) w1s[n * XK + k] = 0;
  }
  // ---- W2 into registers (L2-resident, once per block) ----
  float w2r[8][3];
#pragma unroll
  for (int t = 0; t < 8; ++t)
#pragma unroll
    for (int c = 0; c < 3; ++c) w2r[t][c] = W2[(t * 16 + ln) * 3 + c];
  __syncthreads();  // the only block-wide sync: w1s is read-only below

  const size_t brow0 = (size_t)blockIdx.x * ROWS_PER_BLOCK;
  const int kq = quad * 8;  // this lane's k-offset within a 32-wide k-step

  for (int t = 0; t < NTILES; ++t) {
    // this wave's 32 rows for this tile (two 16-row MFMA sub-tiles)
    const size_t row0 = brow0 + (size_t)t * TILE_ROWS + wave * 32;
    const float* xr0 = x + (row0 + ln) * IN_DIM;       // sub-tile 0: rows row0+ln
    const float* xr1 = xr0 + 16 * IN_DIM;              // sub-tile 1: rows row0+16+ln

    floatx4 acc0[8], acc1[8];
#pragma unroll
    for (int c = 0; c < 8; ++c) {
      acc0[c] = (floatx4)0.f;
      acc1[c] = (floatx4)0.f;
    }

    // ---- layer 1: A-frags straight from global, B-frags from LDS ----
#pragma unroll
    for (int s = 0; s < 5; ++s) {
      const int kb = s * 32 + kq;
      float f0[8], f1[8];
#pragma unroll
      for (int j = 0; j < 8; ++j) {
        const int k = kb + j;
        if (s < 4) {  // compile-time: k <= 127+24+7 < 155, always valid
          f0[j] = xr0[k];
          f1[j] = xr1[k];
        } else {      // tail k-step: k = 128..159, mask k >= 155 (quad 3 only)
          f0[j] = (k < IN_DIM) ? xr0[k] : 0.f;
          f1[j] = (k < IN_DIM) ? xr1[k] : 0.f;
        }
      }
      short8 a0, a1;
#pragma unroll
      for (int j = 0; j < 8; ++j) {
        a0[j] = (short)f2bf(f0[j]);
        a1[j] = (short)f2bf(f1[j]);
      }
#pragma unroll
      for (int t8 = 0; t8 < 8; ++t8) {
        const short8 b = *reinterpret_cast<const short8*>(&w1s[(t8 * 16 + ln) * XK + kb]);
        acc0[t8] = __builtin_amdgcn_mfma_f32_16x16x32_bf16(a0, b, acc0[t8], 0, 0, 0);
        acc1[t8] = __builtin_amdgcn_mfma_f32_16x16x32_bf16(a1, b, acc1[t8], 0, 0, 0);
      }
    }

    // ---- layer 2 + store (register shuffle reduce, no LDS) ----
    epilogue_16rows(acc0, w2r, ln, quad, out, row0);
    epilogue_16rows(acc1, w2r, ln, quad, out, row0 + 16);
    // no __syncthreads: no shared state is written in the tile loop
  }
}

extern "C" void kernel_launch(void* const* d_in, const int* in_sizes, int n_in,
                              void* d_out, int out_size, void* d_ws, size_t ws_size,
                              hipStream_t stream) {
  const float* x = (const float*)d_in[0];
  const float* W1 = (const float*)d_in[1];
  const float* W2 = (const float*)d_in[2];
  float* out = (float*)d_out;
  fused_mlp_kernel<<<dim3(N_TOTAL / ROWS_PER_BLOCK), dim3(256), 0, stream>>>(x, W1, W2, out);
}

// Round 2
// 850.525 us; speedup vs baseline: 1.2689x; 1.2689x over previous
//
#include <hip/hip_runtime.h>

// out = relu(x @ W1) @ W2
// x: [N,155] fp32, W1: [155,128] fp32, W2: [128,3] fp32, out: [N,3] fp32.
// v4: v2's coalesced-staging structure scaled to a 1024-thread block:
//     256-row x tiles, 16 waves (4/SIMD, 1 block/CU), W1^T bf16 + x tile + W2
//     all in LDS (127.5 KiB). Register float4 prefetch issued after the
//     staging barrier so it flies under compute. Epilogue emits ONE coalesced
//     192B store per wave (cndmask select + ds_bpermute) instead of 12
//     single-lane predicated stores (fixes the 13x WRITE_SIZE sector waste).

#define N_TOTAL 1048576
#define IN_DIM 155
#define HIDDEN 128
#define BLOCK_THREADS 1024
#define TILE_ROWS 256
#define NTILES 16
#define ROWS_PER_BLOCK (TILE_ROWS * NTILES)  // 4096
#define XK 168                                // LDS k-stride (bf16): 336B rows, 16B aligned, 2-way-free banks
#define TILE_ELEMS (TILE_ROWS * IN_DIM)       // 39680 floats
#define TILE_F4 (TILE_ELEMS / 4)              // 9920 float4s
#define F4_PER_THREAD 10                      // ceil(9920 / 1024)

typedef __attribute__((ext_vector_type(4))) float fvec4;
typedef __attribute__((ext_vector_type(8))) short short8;   // 8 bf16 MFMA A/B frag
typedef __attribute__((ext_vector_type(4))) float floatx4;  // MFMA C/D frag

static __device__ __forceinline__ unsigned short f2bf(float f) {
  // round-to-nearest-even fp32 -> bf16 (inputs are finite normals)
  unsigned int u = __builtin_bit_cast(unsigned int, f);
  u += 0x7fffu + ((u >> 16) & 1u);
  return (unsigned short)(u >> 16);
}

__global__ __launch_bounds__(1024, 4) void fused_mlp_kernel(
    const float* __restrict__ x, const float* __restrict__ W1,
    const float* __restrict__ W2, float* __restrict__ out) {
  __shared__ __align__(16) unsigned short w1s[HIDDEN * XK];    // 43008 B, W1^T bf16
  __shared__ __align__(16) unsigned short xs[TILE_ROWS * XK];  // 86016 B, x tile bf16
  __shared__ __align__(16) float w2s[HIDDEN * 3];              // 1536 B

  const int tid = threadIdx.x;
  const int ln = tid & 15;
  const int quad = (tid >> 4) & 3;  // 16-lane group within the wave
  const int wave = tid >> 6;
  const int l = tid & 63;

  // ---- stage W1^T as bf16 into LDS ----
  for (int idx = tid; idx < IN_DIM * HIDDEN; idx += BLOCK_THREADS) {
    const int k = idx >> 7;
    const int n = idx & 127;
    w1s[n * XK + k] = f2bf(W1[idx]);
  }
  for (int idx = tid; idx < HIDDEN * 16; idx += BLOCK_THREADS) {  // zero k-pad 155..167
    const int n = idx >> 4;
    const int k = 152 + (idx & 15);
    if (k >= IN_DIM) w1s[n * XK + k] = 0;
  }
  // zero xs k-pad cols 155..167 (never overwritten by staging)
  for (int idx = tid; idx < TILE_ROWS * 13; idx += BLOCK_THREADS) {
    const int r = idx / 13;
    const int c = IN_DIM + (idx - r * 13);
    xs[r * XK + c] = 0;
  }
  // W2 into LDS (keeps VGPR count under the 4-wave/SIMD cap)
  for (int idx = tid; idx < HIDDEN * 3; idx += BLOCK_THREADS) w2s[idx] = W2[idx];
  __syncthreads();

  const size_t block_e0 = (size_t)blockIdx.x * ROWS_PER_BLOCK * IN_DIM;

  // epilogue routing: dst lane l (<48) pulls from src lane 16*(l/12) + (l%12)
  const int srcaddr = ((l / 12) * 16 + (l % 12)) << 2;

  // ---- prefetch tile 0 (flat coalesced float4, 16B aligned) ----
  fvec4 pre[F4_PER_THREAD];
  {
    const fvec4* src = reinterpret_cast<const fvec4*>(x + block_e0);
#pragma unroll
    for (int i = 0; i < F4_PER_THREAD; ++i) {
      const int f = tid + i * BLOCK_THREADS;
      if (f < TILE_F4) pre[i] = src[f];
    }
  }

  for (int t = 0; t < NTILES; ++t) {
    // ---- convert prefetched tile -> xs (bf16, padded rows) ----
#pragma unroll
    for (int i = 0; i < F4_PER_THREAD; ++i) {
      const int f = tid + i * BLOCK_THREADS;
      if (f < TILE_F4) {
        const int e0 = f * 4;
        const int r = e0 / IN_DIM;
        const int c = e0 - r * IN_DIM;
#pragma unroll
        for (int j = 0; j < 4; ++j) {
          const int cc = c + j;
          const int wrap = (cc >= IN_DIM);
          xs[(r + wrap) * XK + (cc - wrap * IN_DIM)] = f2bf(pre[i][j]);
        }
      }
    }
    __syncthreads();

    // ---- issue next tile's loads AFTER the barrier (barrier drains vmcnt;
    //      issued here they stay in flight under compute + epilogue) ----
    if (t + 1 < NTILES) {
      const fvec4* src = reinterpret_cast<const fvec4*>(
          x + block_e0 + (size_t)(t + 1) * TILE_ELEMS);
#pragma unroll
      for (int i = 0; i < F4_PER_THREAD; ++i) {
        const int f = tid + i * BLOCK_THREADS;
        if (f < TILE_F4) pre[i] = src[f];
      }
    }

    // ---- layer 1: 16 rows per wave, B-frags from LDS ----
    floatx4 acc[8];
#pragma unroll
    for (int c8 = 0; c8 < 8; ++c8) acc[c8] = (floatx4)0.f;
    const int rbase = wave * 16;
#pragma unroll
    for (int s = 0; s < 5; ++s) {
      const int kb = s * 32 + quad * 8;
      const short8 a = *reinterpret_cast<const short8*>(&xs[(rbase + ln) * XK + kb]);
#pragma unroll
      for (int t8 = 0; t8 < 8; ++t8) {
        const short8 b = *reinterpret_cast<const short8*>(&w1s[(t8 * 16 + ln) * XK + kb]);
        acc[t8] = __builtin_amdgcn_mfma_f32_16x16x32_bf16(a, b, acc[t8], 0, 0, 0);
      }
    }

    // ---- layer 2: relu + W2, reduce across 16-lane group ----
    // acc[t8][r] = h[row0 + quad*4 + r][16*t8 + ln]
    float part[4][3];
#pragma unroll
    for (int r = 0; r < 4; ++r)
#pragma unroll
      for (int c = 0; c < 3; ++c) part[r][c] = 0.f;
#pragma unroll
    for (int t8 = 0; t8 < 8; ++t8) {
      const float wa = w2s[(t8 * 16 + ln) * 3 + 0];
      const float wb = w2s[(t8 * 16 + ln) * 3 + 1];
      const float wc = w2s[(t8 * 16 + ln) * 3 + 2];
#pragma unroll
      for (int r = 0; r < 4; ++r) {
        const float hv = fmaxf(acc[t8][r], 0.f);
        part[r][0] = fmaf(hv, wa, part[r][0]);
        part[r][1] = fmaf(hv, wb, part[r][1]);
        part[r][2] = fmaf(hv, wc, part[r][2]);
      }
    }
#pragma unroll
    for (int off = 1; off < 16; off <<= 1) {
#pragma unroll
      for (int r = 0; r < 4; ++r)
#pragma unroll
        for (int c = 0; c < 3; ++c) part[r][c] += __shfl_xor(part[r][c], off, 16);
    }

    // ---- single coalesced 192B store per wave ----
    // every lane of a 16-lane group now holds all 12 sums for its 4 rows;
    // lane j (j<12) of each group selects part[j/3][j%3] (static cndmask tree),
    // then dst lane l pulls from lane 16*(l/12) + (l%12).
    float v = part[0][0];
    v = (ln == 1) ? part[0][1] : v;
    v = (ln == 2) ? part[0][2] : v;
    v = (ln == 3) ? part[1][0] : v;
    v = (ln == 4) ? part[1][1] : v;
    v = (ln == 5) ? part[1][2] : v;
    v = (ln == 6) ? part[2][0] : v;
    v = (ln == 7) ? part[2][1] : v;
    v = (ln == 8) ? part[2][2] : v;
    v = (ln == 9) ? part[3][0] : v;
    v = (ln == 10) ? part[3][1] : v;
    v = (ln == 11) ? part[3][2] : v;
    const int vo = __builtin_amdgcn_ds_bpermute(srcaddr, __builtin_bit_cast(int, v));
    const size_t row0 =
        (size_t)blockIdx.x * ROWS_PER_BLOCK + (size_t)t * TILE_ROWS + wave * 16;
    if (l < 48) out[row0 * 3 + l] = __builtin_bit_cast(float, vo);

    __syncthreads();  // all waves done reading xs before next overwrite
  }
}

extern "C" void kernel_launch(void* const* d_in, const int* in_sizes, int n_in,
                              void* d_out, int out_size, void* d_ws, size_t ws_size,
                              hipStream_t stream) {
  const float* x = (const float*)d_in[0];
  const float* W1 = (const float*)d_in[1];
  const float* W2 = (const float*)d_in[2];
  float* out = (float*)d_out;
  fused_mlp_kernel<<<dim3(N_TOTAL / ROWS_PER_BLOCK), dim3(BLOCK_THREADS), 0, stream>>>(
      x, W1, W2, out);
}